// Round 1
// 215.412 us; speedup vs baseline: 1.1489x; 1.1489x over previous
//
#include <hip/hip_runtime.h>
#include <hip/hip_bf16.h>
#include <stdint.h>

// Problem constants: B=4, S=1024, E=512, H=8, D=64
#define S_LEN 1024
#define E_DIM 512
#define H_NUM 8
#define D_DIM 64
#define B_NUM 4
#define BH_NUM 32

using s16x8 = __attribute__((ext_vector_type(8))) short;           // 8 bf16 (4 VGPRs)
using f32x4 = __attribute__((ext_vector_type(4))) float;           // MFMA accumulator
using us4   = __attribute__((ext_vector_type(4))) unsigned short;  // 4 bf16 (8 B)

typedef const __attribute__((address_space(1))) uint32_t gas_uint;
typedef __attribute__((address_space(3))) uint32_t las_uint;

static __device__ __forceinline__ unsigned short f2bf(float f) {
  __hip_bfloat16 h = __float2bfloat16(f);
  return __builtin_bit_cast(unsigned short, h);
}
static __device__ __forceinline__ float bf2f(unsigned short u) {
  return __bfloat162float(__builtin_bit_cast(__hip_bfloat16, u));
}

// ---------------------------------------------------------------------------
// K_PREP: fused recurrence + pack + transpose (block-range dispatch).
// ---------------------------------------------------------------------------
#define NB_RECUR 8
#define NB_PACK  2048
#define NB_TR    512

__global__ __launch_bounds__(256) void k_prep(const float* __restrict__ src,
                                              const float* __restrict__ tgt,
                                              const float* __restrict__ enc,
                                              __hip_bfloat16* __restrict__ qb,
                                              __hip_bfloat16* __restrict__ kb,
                                              __hip_bfloat16* __restrict__ cb,
                                              __hip_bfloat16* __restrict__ tT) {
  __shared__ float tile[64][65];                   // used by transpose branch only
  const int bid = blockIdx.x;
  const int tid = threadIdx.x;

  if (bid < NB_RECUR) {
    // ---- serial recurrence: c_t = tanh(cc*pe); cc' = k_t*c_t; cc_0 = k_0 ----
    int g = bid * 256 + tid;                       // 0..2047
    int d = g & 63;
    int bh = g >> 6;
    int h = bh & 7;
    int b = bh >> 3;
    float pe = enc[h * D_DIM + d];
    float pe2 = 2.0f * pe;                         // tanh(x)=sgn(x)(1-e)/(1+e), e=exp(-2|x|)
    const float* tp = tgt + (size_t)b * S_LEN * E_DIM + h * D_DIM + d;
    __hip_bfloat16* cp = cb + (size_t)bh * S_LEN * D_DIM + d;

    constexpr int CH = 32;                         // prefetch chunk (registers)
    float bufA[CH], bufB[CH];
#pragma unroll
    for (int i = 0; i < CH; ++i) bufA[i] = tp[(size_t)i * E_DIM];
    float cc = bufA[0];                            // carry_0 = k_0

#pragma unroll 1
    for (int ch = 0; ch < S_LEN / CH; ch += 2) {
      if (ch + 1 < S_LEN / CH) {
#pragma unroll
        for (int i = 0; i < CH; ++i)
          bufB[i] = tp[(size_t)((ch + 1) * CH + i) * E_DIM];
      }
#pragma unroll
      for (int i = 0; i < CH; ++i) {
        float m = cc * pe2;
        float e = __expf(-fabsf(m));               // abs/neg fold to input mods
        float th = __builtin_copysignf((1.0f - e) * __builtin_amdgcn_rcpf(1.0f + e), m);
        cp[(size_t)(ch * CH + i) * D_DIM] = __float2bfloat16(th);
        cc = bufA[i] * th;
      }
      if (ch + 2 < S_LEN / CH) {
#pragma unroll
        for (int i = 0; i < CH; ++i)
          bufA[i] = tp[(size_t)((ch + 2) * CH + i) * E_DIM];
      }
#pragma unroll
      for (int i = 0; i < CH; ++i) {
        float m = cc * pe2;
        float e = __expf(-fabsf(m));
        float th = __builtin_copysignf((1.0f - e) * __builtin_amdgcn_rcpf(1.0f + e), m);
        cp[(size_t)((ch + 1) * CH + i) * D_DIM] = __float2bfloat16(th);
        cc = bufB[i] * th;
      }
    }
  } else if (bid < NB_RECUR + NB_PACK) {
    // ---- pack src/tgt (b,s,e) fp32 -> (bh,s,d) bf16, 4 elts/thread ----
    size_t i4 = ((size_t)(bid - NB_RECUR) * 256 + tid) * 4;   // < 2M
    float4 s4 = *reinterpret_cast<const float4*>(src + i4);
    float4 t4 = *reinterpret_cast<const float4*>(tgt + i4);
    int e = (int)(i4 & 511);                       // e%4==0, within one head (D=64)
    size_t bs = i4 >> 9;
    int s = (int)(bs & 1023);
    int b = (int)(bs >> 10);
    int h = e >> 6, d = e & 63;
    size_t o = (((size_t)(b * H_NUM + h) * S_LEN) + s) * D_DIM + d;
    us4 qv = {f2bf(s4.x), f2bf(s4.y), f2bf(s4.z), f2bf(s4.w)};
    us4 kv = {f2bf(t4.x), f2bf(t4.y), f2bf(t4.z), f2bf(t4.w)};
    *reinterpret_cast<us4*>(qb + o) = qv;
    *reinterpret_cast<us4*>(kb + o) = kv;
  } else {
    // ---- transpose tgt (b,s,e) -> tT (b,e,s) bf16, 64x64 tiles ----
    int lb = bid - (NB_RECUR + NB_PACK);           // 0..511
    int sx = lb & 15, ey = (lb >> 4) & 7, b = lb >> 7;
    int e0 = ey * 64, s0 = sx * 64;
    int tx = tid & 63, ty = tid >> 6;              // ty 0..3
    const float* p = tgt + ((size_t)b * S_LEN + s0) * E_DIM + e0;
#pragma unroll
    for (int r = ty; r < 64; r += 4) tile[r][tx] = p[(size_t)r * E_DIM + tx];
    __syncthreads();
    __hip_bfloat16* q = tT + ((size_t)b * E_DIM + e0) * S_LEN + s0;
#pragma unroll
    for (int r = ty; r < 64; r += 4) q[(size_t)r * S_LEN + tx] = __float2bfloat16(tile[tx][r]);
  }
}

// ---------------------------------------------------------------------------
// K3: attention weights.
// v2: P1 load sweep is now a per-wave depth-2 pipeline through LDS:
//   - c/k fragment tiles staged with global_load_lds (no VGPR cost, so the
//     96-reg softmax state no longer blocks prefetch),
//   - 3-buffer rotation + counted s_waitcnt vmcnt(4) (never 0 in steady
//     state): stage(it) complete, stage(it+1) in flight, stage(it+2) issued
//     after the MFMAs — L2/L3 latency hidden under exp/pack VALU,
//   - XOR swizzle byte^=((row&7)<<4) applied as inverse-swizzled GLOBAL
//     source + swizzled ds_read (rule 21): [16][128B] row reads would be a
//     32-way bank conflict otherwise,
//   - per-wave staging => no extra barriers; s_setprio(1) around MFMAs.
// Everything downstream (reduce, P2 register pass, P3 writes) unchanged.
// ---------------------------------------------------------------------------
__global__ __launch_bounds__(256) void k_weights(const __hip_bfloat16* __restrict__ qb,
                                                 const __hip_bfloat16* __restrict__ kb,
                                                 const __hip_bfloat16* __restrict__ cb,
                                                 __hip_bfloat16* __restrict__ wt,
                                                 const float* __restrict__ pal,
                                                 const float* __restrict__ pbe,
                                                 const float* __restrict__ pga) {
  // [wave][buf][c: ushort 0..1023 | k: ushort 1024..2047]  => 48 KB
  __shared__ unsigned short stage[4][3][2048];
  __shared__ float red0[4][16];                    // per-wave l_g partials
  __shared__ float red1[4][16];                    // per-wave l_w partials

  const int tid = threadIdx.x;
  const int wave = tid >> 6, lane = tid & 63;
  const int quad = lane >> 4, col = lane & 15;

  // XCD-aware decode: xcd = g&7 (round-robin), r enumerates (bh-sub, s-tile)
  const int g = blockIdx.x;
  const int xcd = g & 7;
  const int r = g >> 3;                            // 0..255
  const int bh = xcd * 4 + (r >> 6);               // 4 bh per XCD
  const int s0 = (r & 63) * 16;

  const float alpha = pal[0], beta = pbe[0];
  const float inv_gamma = 1.0f / pga[0];
  const float sa = alpha * 0.01f * inv_gamma;      // semantic scale folded
  const float sb = beta * inv_gamma;

  // A fragments (Q rows s0..s0+15), loaded once, shared by both GEMMs.
  const __hip_bfloat16* qrow = qb + ((size_t)bh * S_LEN + s0 + col) * D_DIM;
  s16x8 a0 = *reinterpret_cast<const s16x8*>(qrow + quad * 8);
  s16x8 a1 = *reinterpret_cast<const s16x8*>(qrow + 32 + quad * 8);

  const int t_base = wave * 256;
  uint32_t stg[16][2];                             // g~ packed bf16 pairs (32 regs)
  float    stk[16][4];                             // qk logits fp32 (64 regs)

  // ---- pass 1: pipelined fused QC^T + QK^T sweep ----
  // Staging geometry: per iter, c tile = rows t_base+it*16..+15, 16 rows x
  // 128 B contiguous (2 KB) => 2 global_load_lds dwordx4 ops; same for k.
  // Linear LDS dest (base + lane*16); global src byte for dest d:
  //   (d & ~127) | ((d&127) ^ ((row&7)<<4)),  row = d>>7.
  const char* cbase = (const char*)(cb + ((size_t)bh * S_LEN + t_base) * D_DIM);
  const char* kbase = (const char*)(kb + ((size_t)bh * S_LEN + t_base) * D_DIM);
  const int so0 = ((lane >> 3) << 7) | (((lane & 7) ^ ((lane >> 3) & 7)) << 4);

  auto stage_it = [&](int it) {
    unsigned short* db = &stage[wave][it % 3][0];
    const char* cs = cbase + it * 2048;
    const char* ks = kbase + it * 2048;
    __builtin_amdgcn_global_load_lds((gas_uint*)(cs + so0),        (las_uint*)(db),        16, 0, 0);
    __builtin_amdgcn_global_load_lds((gas_uint*)(cs + so0 + 1024), (las_uint*)(db + 512),  16, 0, 0);
    __builtin_amdgcn_global_load_lds((gas_uint*)(ks + so0),        (las_uint*)(db + 1024), 16, 0, 0);
    __builtin_amdgcn_global_load_lds((gas_uint*)(ks + so0 + 1024), (las_uint*)(db + 1536), 16, 0, 0);
  };

  stage_it(0);
  stage_it(1);

  const int xswz = (col & 7) << 4;                 // read-side swizzle (row = col)
  float lg[4] = {0.f, 0.f, 0.f, 0.f};
#pragma unroll
  for (int it = 0; it < 16; ++it) {
    // steady state: stage(it) done, stage(it+1)'s 4 ops still in flight.
    if (it < 15) asm volatile("s_waitcnt vmcnt(4)" ::: "memory");
    else         asm volatile("s_waitcnt vmcnt(0)" ::: "memory");
    const char* cw = (const char*)&stage[wave][it % 3][0];
    const char* kw = cw + 2048;
    const int rb = col * 128;
    s16x8 cf0 = *reinterpret_cast<const s16x8*>(cw + rb + ((quad * 16) ^ xswz));
    s16x8 cf1 = *reinterpret_cast<const s16x8*>(cw + rb + ((64 + quad * 16) ^ xswz));
    s16x8 kf0 = *reinterpret_cast<const s16x8*>(kw + rb + ((quad * 16) ^ xswz));
    s16x8 kf1 = *reinterpret_cast<const s16x8*>(kw + rb + ((64 + quad * 16) ^ xswz));
    f32x4 dg = {0.f, 0.f, 0.f, 0.f};
    f32x4 dk = {0.f, 0.f, 0.f, 0.f};
    __builtin_amdgcn_s_setprio(1);
    dg = __builtin_amdgcn_mfma_f32_16x16x32_bf16(a0, cf0, dg, 0, 0, 0);
    dg = __builtin_amdgcn_mfma_f32_16x16x32_bf16(a1, cf1, dg, 0, 0, 0);
    dk = __builtin_amdgcn_mfma_f32_16x16x32_bf16(a0, kf0, dk, 0, 0, 0);
    dk = __builtin_amdgcn_mfma_f32_16x16x32_bf16(a1, kf1, dk, 0, 0, 0);
    __builtin_amdgcn_s_setprio(0);
    // buf (it+2)%3 was read at it-1 and consumed by those MFMAs (lgkmcnt
    // drained before MFMA issue) => safe to overwrite now.
    if (it + 2 < 16) stage_it(it + 2);
    uint32_t p0 = 0, p1 = 0;
#pragma unroll
    for (int i = 0; i < 4; ++i) {
      float gv = __expf(dg[i] * 0.125f);           // /sqrt(D)
      unsigned short u = f2bf(gv);
      lg[i] += bf2f(u);                            // sum the ROUNDED value (consistent)
      if (i < 2) p0 |= (uint32_t)u << (16 * i);
      else       p1 |= (uint32_t)u << (16 * (i - 2));
      stk[it][i] = dk[i];
    }
    stg[it][0] = p0;
    stg[it][1] = p1;
  }
#pragma unroll
  for (int m = 1; m < 16; m <<= 1) {
#pragma unroll
    for (int i = 0; i < 4; ++i) lg[i] += __shfl_xor(lg[i], m);
  }
  if (col == 0) {
#pragma unroll
    for (int i = 0; i < 4; ++i) red0[wave][quad * 4 + i] = lg[i];
  }
  __syncthreads();
  float ilg[4];
#pragma unroll
  for (int i = 0; i < 4; ++i) {
    int rr = quad * 4 + i;
    ilg[i] = 1.0f / (red0[0][rr] + red0[1][rr] + red0[2][rr] + red0[3][rr]);
  }

  // ---- pass 2 (register-only): combine + l_w ----
  float lw[4] = {0.f, 0.f, 0.f, 0.f};
#pragma unroll
  for (int it = 0; it < 16; ++it) {
#pragma unroll
    for (int i = 0; i < 4; ++i) {
      unsigned short u = (unsigned short)((i < 2 ? stg[it][0] >> (16 * i)
                                                 : stg[it][1] >> (16 * (i - 2))) & 0xffffu);
      float gv = bf2f(u) * ilg[i];
      float z = sa * stk[it][i] + sb * gv;
      float wv = __expf(z);
      stk[it][i] = wv;
      lw[i] += wv;
    }
  }
#pragma unroll
  for (int m = 1; m < 16; m <<= 1) {
#pragma unroll
    for (int i = 0; i < 4; ++i) lw[i] += __shfl_xor(lw[i], m);
  }
  if (col == 0) {
#pragma unroll
    for (int i = 0; i < 4; ++i) red1[wave][quad * 4 + i] = lw[i];
  }
  __syncthreads();
  float ilw[4];
#pragma unroll
  for (int i = 0; i < 4; ++i) {
    int rr = quad * 4 + i;
    ilw[i] = 1.0f / (red1[0][rr] + red1[1][rr] + red1[2][rr] + red1[3][rr]);
  }

  // ---- pass 3: normalize + write wt (t, s) layout ----
  __hip_bfloat16* wrow = wt + ((size_t)bh * S_LEN + t_base + col) * S_LEN + s0 + quad * 4;
#pragma unroll
  for (int it = 0; it < 16; ++it) {
    us4 o;
#pragma unroll
    for (int i = 0; i < 4; ++i) o[i] = f2bf(stk[it][i] * ilw[i]);
    *reinterpret_cast<us4*>(wrow + (size_t)it * 16 * S_LEN) = o;
  }
}

// ---------------------------------------------------------------------------
// K4: out[bh, t, e] = sum_s wt[bh][t][s] * tT[b][e][s]   (BT-GEMM, m97 style)
// Tile 128(m=t) x 128(n=e), BK=64(k=s). 256 thr; wave -> 64x64 subtile.
// 1D grid with XCD-aware swizzle (wt A-strip + tT locality per XCD).
// ---------------------------------------------------------------------------
__global__ __launch_bounds__(256) void k_outgemm(const __hip_bfloat16* __restrict__ wt,
                                                 const __hip_bfloat16* __restrict__ tT,
                                                 float* __restrict__ out) {
  __shared__ __hip_bfloat16 As[128 * 64];          // [m][k] 16 KB
  __shared__ __hip_bfloat16 Bs[128 * 64];          // [n][k] 16 KB
  const int tid = threadIdx.x;
  const int wave = tid >> 6, lane = tid & 63;
  const int quad = lane >> 4, col = lane & 15;

  const int g = blockIdx.x;                        // 0..1023
  const int xcd = g & 7;
  const int local = g >> 3;                        // 0..127
  const int strip = xcd * 32 + (local >> 2);       // 0..255 = (bh, mtile)
  const int ntile = local & 3;
  const int bh = strip >> 3;
  const int mt = strip & 7;
  const int b = bh >> 3;
  const int m0 = mt * 128;                         // t
  const int n0 = ntile * 128;                      // e

  const __hip_bfloat16* Ag = wt + (size_t)bh * S_LEN * S_LEN;   // row stride S
  const __hip_bfloat16* Bg = tT + (size_t)b * E_DIM * S_LEN;    // row stride S
  const int mw = (wave >> 1) * 64, nw = (wave & 1) * 64;
  const int lrow = lane >> 3;                      // 0..7
  const int lcol = (lane & 7) * 8;                 // element col offset

  f32x4 acc[4][4];
#pragma unroll
  for (int i = 0; i < 4; ++i)
#pragma unroll
    for (int j = 0; j < 4; ++j) acc[i][j] = (f32x4){0.f, 0.f, 0.f, 0.f};

  for (int kt = 0; kt < 16; ++kt) {
    const int k0 = kt * 64;
    __syncthreads();                               // protect LDS from prior reads
#pragma unroll
    for (int j = 0; j < 4; ++j) {                  // stage A: 4x16B per thread
      int row = j * 32 + wave * 8 + lrow;
      const __hip_bfloat16* gp = Ag + (size_t)(m0 + row) * S_LEN + k0 + lcol;
      __builtin_amdgcn_global_load_lds((gas_uint*)gp,
                                       (las_uint*)(As + (j * 32 + wave * 8) * 64),
                                       16, 0, 0);
    }
#pragma unroll
    for (int j = 0; j < 4; ++j) {                  // stage B
      int row = j * 32 + wave * 8 + lrow;
      const __hip_bfloat16* gp = Bg + (size_t)(n0 + row) * S_LEN + k0 + lcol;
      __builtin_amdgcn_global_load_lds((gas_uint*)gp,
                                       (las_uint*)(Bs + (j * 32 + wave * 8) * 64),
                                       16, 0, 0);
    }
    __syncthreads();                               // drain vmcnt + barrier
#pragma unroll
    for (int ks = 0; ks < 2; ++ks) {
      s16x8 af[4], bf[4];
#pragma unroll
      for (int i = 0; i < 4; ++i)
        af[i] = *reinterpret_cast<const s16x8*>(As + (mw + i * 16 + col) * 64 + ks * 32 + quad * 8);
#pragma unroll
      for (int i = 0; i < 4; ++i)
        bf[i] = *reinterpret_cast<const s16x8*>(Bs + (nw + i * 16 + col) * 64 + ks * 32 + quad * 8);
#pragma unroll
      for (int mi = 0; mi < 4; ++mi)
#pragma unroll
        for (int ni = 0; ni < 4; ++ni)
          acc[mi][ni] = __builtin_amdgcn_mfma_f32_16x16x32_bf16(af[mi], bf[ni], acc[mi][ni], 0, 0, 0);
    }
  }

  // epilogue: C row = quad*4+reg (m), col = lane&15 (n)
#pragma unroll
  for (int mi = 0; mi < 4; ++mi)
#pragma unroll
    for (int ni = 0; ni < 4; ++ni)
#pragma unroll
      for (int i = 0; i < 4; ++i) {
        int m = m0 + mw + mi * 16 + quad * 4 + i;
        int n = n0 + nw + ni * 16 + col;
        out[((size_t)bh * S_LEN + m) * E_DIM + n] = acc[mi][ni][i];
      }
}

// ---------------------------------------------------------------------------
// Workspace layout (bytes):
//   qb  [0,   4M)   (BH,S,D) bf16
//   kb  [4M,  8M)
//   cb  [8M, 12M)
//   tT  [12M,16M)   (B,E,S) bf16
//   wt  [16M,80M)   (BH,S_t,S_s) bf16
// ---------------------------------------------------------------------------
extern "C" void kernel_launch(void* const* d_in, const int* in_sizes, int n_in,
                              void* d_out, int out_size, void* d_ws, size_t ws_size,
                              hipStream_t stream) {
  (void)in_sizes; (void)n_in; (void)out_size; (void)ws_size;
  const float* src = (const float*)d_in[0];
  const float* tgt = (const float*)d_in[1];
  const float* enc = (const float*)d_in[2];
  const float* pal = (const float*)d_in[3];
  const float* pbe = (const float*)d_in[4];
  const float* pga = (const float*)d_in[5];
  float* out = (float*)d_out;

  char* ws = (char*)d_ws;
  __hip_bfloat16* qb = (__hip_bfloat16*)(ws);
  __hip_bfloat16* kb = (__hip_bfloat16*)(ws + ((size_t)4 << 20));
  __hip_bfloat16* cb = (__hip_bfloat16*)(ws + ((size_t)8 << 20));
  __hip_bfloat16* tT = (__hip_bfloat16*)(ws + ((size_t)12 << 20));
  __hip_bfloat16* wt = (__hip_bfloat16*)(ws + ((size_t)16 << 20));

  // Fused prep: recurrence (blocks 0..7) + pack + transpose
  k_prep<<<NB_RECUR + NB_PACK + NB_TR, 256, 0, stream>>>(src, tgt, enc, qb, kb, cb, tT);
  // K3: weights (1D swizzled grid, 4 bh per XCD)
  k_weights<<<dim3((S_LEN / 16) * BH_NUM), 256, 0, stream>>>(qb, kb, cb, wt, pal, pbe, pga);
  // K4: output GEMM (1D swizzled grid)
  k_outgemm<<<dim3((E_DIM / 128) * (S_LEN / 128) * BH_NUM), 256, 0, stream>>>(wt, tT, out);
}

// Round 2
// 204.313 us; speedup vs baseline: 1.2113x; 1.0543x over previous
//
#include <hip/hip_runtime.h>
#include <hip/hip_bf16.h>
#include <stdint.h>

// Problem constants: B=4, S=1024, E=512, H=8, D=64
#define S_LEN 1024
#define E_DIM 512
#define H_NUM 8
#define D_DIM 64
#define B_NUM 4
#define BH_NUM 32

using s16x8 = __attribute__((ext_vector_type(8))) short;           // 8 bf16 (4 VGPRs)
using f32x4 = __attribute__((ext_vector_type(4))) float;           // MFMA accumulator
using us4   = __attribute__((ext_vector_type(4))) unsigned short;  // 4 bf16 (8 B)

typedef const __attribute__((address_space(1))) uint32_t gas_uint;
typedef __attribute__((address_space(3))) uint32_t las_uint;

static __device__ __forceinline__ unsigned short f2bf(float f) {
  __hip_bfloat16 h = __float2bfloat16(f);
  return __builtin_bit_cast(unsigned short, h);
}
static __device__ __forceinline__ float bf2f(unsigned short u) {
  return __bfloat162float(__builtin_bit_cast(__hip_bfloat16, u));
}

// ---------------------------------------------------------------------------
// K_PREP: fused recurrence + pack + transpose (block-range dispatch).
// ---------------------------------------------------------------------------
#define NB_RECUR 8
#define NB_PACK  2048
#define NB_TR    512

__global__ __launch_bounds__(256) void k_prep(const float* __restrict__ src,
                                              const float* __restrict__ tgt,
                                              const float* __restrict__ enc,
                                              __hip_bfloat16* __restrict__ qb,
                                              __hip_bfloat16* __restrict__ kb,
                                              __hip_bfloat16* __restrict__ cb,
                                              __hip_bfloat16* __restrict__ tT) {
  __shared__ float tile[64][65];                   // used by transpose branch only
  const int bid = blockIdx.x;
  const int tid = threadIdx.x;

  if (bid < NB_RECUR) {
    // ---- serial recurrence: c_t = tanh(cc*pe); cc' = k_t*c_t; cc_0 = k_0 ----
    int g = bid * 256 + tid;                       // 0..2047
    int d = g & 63;
    int bh = g >> 6;
    int h = bh & 7;
    int b = bh >> 3;
    float pe = enc[h * D_DIM + d];
    float pe2 = 2.0f * pe;                         // tanh(x)=sgn(x)(1-e)/(1+e), e=exp(-2|x|)
    const float* tp = tgt + (size_t)b * S_LEN * E_DIM + h * D_DIM + d;
    __hip_bfloat16* cp = cb + (size_t)bh * S_LEN * D_DIM + d;

    constexpr int CH = 32;                         // prefetch chunk (registers)
    float bufA[CH], bufB[CH];
#pragma unroll
    for (int i = 0; i < CH; ++i) bufA[i] = tp[(size_t)i * E_DIM];
    float cc = bufA[0];                            // carry_0 = k_0

#pragma unroll 1
    for (int ch = 0; ch < S_LEN / CH; ch += 2) {
      if (ch + 1 < S_LEN / CH) {
#pragma unroll
        for (int i = 0; i < CH; ++i)
          bufB[i] = tp[(size_t)((ch + 1) * CH + i) * E_DIM];
      }
#pragma unroll
      for (int i = 0; i < CH; ++i) {
        float m = cc * pe2;
        float e = __expf(-fabsf(m));               // abs/neg fold to input mods
        float th = __builtin_copysignf((1.0f - e) * __builtin_amdgcn_rcpf(1.0f + e), m);
        cp[(size_t)(ch * CH + i) * D_DIM] = __float2bfloat16(th);
        cc = bufA[i] * th;
      }
      if (ch + 2 < S_LEN / CH) {
#pragma unroll
        for (int i = 0; i < CH; ++i)
          bufA[i] = tp[(size_t)((ch + 2) * CH + i) * E_DIM];
      }
#pragma unroll
      for (int i = 0; i < CH; ++i) {
        float m = cc * pe2;
        float e = __expf(-fabsf(m));
        float th = __builtin_copysignf((1.0f - e) * __builtin_amdgcn_rcpf(1.0f + e), m);
        cp[(size_t)((ch + 1) * CH + i) * D_DIM] = __float2bfloat16(th);
        cc = bufB[i] * th;
      }
    }
  } else if (bid < NB_RECUR + NB_PACK) {
    // ---- pack src/tgt (b,s,e) fp32 -> (bh,s,d) bf16, 4 elts/thread ----
    size_t i4 = ((size_t)(bid - NB_RECUR) * 256 + tid) * 4;   // < 2M
    float4 s4 = *reinterpret_cast<const float4*>(src + i4);
    float4 t4 = *reinterpret_cast<const float4*>(tgt + i4);
    int e = (int)(i4 & 511);                       // e%4==0, within one head (D=64)
    size_t bs = i4 >> 9;
    int s = (int)(bs & 1023);
    int b = (int)(bs >> 10);
    int h = e >> 6, d = e & 63;
    size_t o = (((size_t)(b * H_NUM + h) * S_LEN) + s) * D_DIM + d;
    us4 qv = {f2bf(s4.x), f2bf(s4.y), f2bf(s4.z), f2bf(s4.w)};
    us4 kv = {f2bf(t4.x), f2bf(t4.y), f2bf(t4.z), f2bf(t4.w)};
    *reinterpret_cast<us4*>(qb + o) = qv;
    *reinterpret_cast<us4*>(kb + o) = kv;
  } else {
    // ---- transpose tgt (b,s,e) -> tT (b,e,s) bf16, 64x64 tiles ----
    int lb = bid - (NB_RECUR + NB_PACK);           // 0..511
    int sx = lb & 15, ey = (lb >> 4) & 7, b = lb >> 7;
    int e0 = ey * 64, s0 = sx * 64;
    int tx = tid & 63, ty = tid >> 6;              // ty 0..3
    const float* p = tgt + ((size_t)b * S_LEN + s0) * E_DIM + e0;
#pragma unroll
    for (int r = ty; r < 64; r += 4) tile[r][tx] = p[(size_t)r * E_DIM + tx];
    __syncthreads();
    __hip_bfloat16* q = tT + ((size_t)b * E_DIM + e0) * S_LEN + s0;
#pragma unroll
    for (int r = ty; r < 64; r += 4) q[(size_t)r * S_LEN + tx] = __float2bfloat16(tile[tx][r]);
  }
}

// ---------------------------------------------------------------------------
// K3: attention weights (v2 pipelined — unchanged this round).
// ---------------------------------------------------------------------------
__global__ __launch_bounds__(256) void k_weights(const __hip_bfloat16* __restrict__ qb,
                                                 const __hip_bfloat16* __restrict__ kb,
                                                 const __hip_bfloat16* __restrict__ cb,
                                                 __hip_bfloat16* __restrict__ wt,
                                                 const float* __restrict__ pal,
                                                 const float* __restrict__ pbe,
                                                 const float* __restrict__ pga) {
  // [wave][buf][c: ushort 0..1023 | k: ushort 1024..2047]  => 48 KB
  __shared__ unsigned short stage[4][3][2048];
  __shared__ float red0[4][16];                    // per-wave l_g partials
  __shared__ float red1[4][16];                    // per-wave l_w partials

  const int tid = threadIdx.x;
  const int wave = tid >> 6, lane = tid & 63;
  const int quad = lane >> 4, col = lane & 15;

  // XCD-aware decode: xcd = g&7 (round-robin), r enumerates (bh-sub, s-tile)
  const int g = blockIdx.x;
  const int xcd = g & 7;
  const int r = g >> 3;                            // 0..255
  const int bh = xcd * 4 + (r >> 6);               // 4 bh per XCD
  const int s0 = (r & 63) * 16;

  const float alpha = pal[0], beta = pbe[0];
  const float inv_gamma = 1.0f / pga[0];
  const float sa = alpha * 0.01f * inv_gamma;      // semantic scale folded
  const float sb = beta * inv_gamma;

  // A fragments (Q rows s0..s0+15), loaded once, shared by both GEMMs.
  const __hip_bfloat16* qrow = qb + ((size_t)bh * S_LEN + s0 + col) * D_DIM;
  s16x8 a0 = *reinterpret_cast<const s16x8*>(qrow + quad * 8);
  s16x8 a1 = *reinterpret_cast<const s16x8*>(qrow + 32 + quad * 8);

  const int t_base = wave * 256;
  uint32_t stg[16][2];                             // g~ packed bf16 pairs (32 regs)
  float    stk[16][4];                             // qk logits fp32 (64 regs)

  // ---- pass 1: pipelined fused QC^T + QK^T sweep ----
  const char* cbase = (const char*)(cb + ((size_t)bh * S_LEN + t_base) * D_DIM);
  const char* kbase = (const char*)(kb + ((size_t)bh * S_LEN + t_base) * D_DIM);
  const int so0 = ((lane >> 3) << 7) | (((lane & 7) ^ ((lane >> 3) & 7)) << 4);

  auto stage_it = [&](int it) {
    unsigned short* db = &stage[wave][it % 3][0];
    const char* cs = cbase + it * 2048;
    const char* ks = kbase + it * 2048;
    __builtin_amdgcn_global_load_lds((gas_uint*)(cs + so0),        (las_uint*)(db),        16, 0, 0);
    __builtin_amdgcn_global_load_lds((gas_uint*)(cs + so0 + 1024), (las_uint*)(db + 512),  16, 0, 0);
    __builtin_amdgcn_global_load_lds((gas_uint*)(ks + so0),        (las_uint*)(db + 1024), 16, 0, 0);
    __builtin_amdgcn_global_load_lds((gas_uint*)(ks + so0 + 1024), (las_uint*)(db + 1536), 16, 0, 0);
  };

  stage_it(0);
  stage_it(1);

  const int xswz = (col & 7) << 4;                 // read-side swizzle (row = col)
  float lg[4] = {0.f, 0.f, 0.f, 0.f};
#pragma unroll
  for (int it = 0; it < 16; ++it) {
    // steady state: stage(it) done, stage(it+1)'s 4 ops still in flight.
    if (it < 15) asm volatile("s_waitcnt vmcnt(4)" ::: "memory");
    else         asm volatile("s_waitcnt vmcnt(0)" ::: "memory");
    const char* cw = (const char*)&stage[wave][it % 3][0];
    const char* kw = cw + 2048;
    const int rb = col * 128;
    s16x8 cf0 = *reinterpret_cast<const s16x8*>(cw + rb + ((quad * 16) ^ xswz));
    s16x8 cf1 = *reinterpret_cast<const s16x8*>(cw + rb + ((64 + quad * 16) ^ xswz));
    s16x8 kf0 = *reinterpret_cast<const s16x8*>(kw + rb + ((quad * 16) ^ xswz));
    s16x8 kf1 = *reinterpret_cast<const s16x8*>(kw + rb + ((64 + quad * 16) ^ xswz));
    f32x4 dg = {0.f, 0.f, 0.f, 0.f};
    f32x4 dk = {0.f, 0.f, 0.f, 0.f};
    __builtin_amdgcn_s_setprio(1);
    dg = __builtin_amdgcn_mfma_f32_16x16x32_bf16(a0, cf0, dg, 0, 0, 0);
    dg = __builtin_amdgcn_mfma_f32_16x16x32_bf16(a1, cf1, dg, 0, 0, 0);
    dk = __builtin_amdgcn_mfma_f32_16x16x32_bf16(a0, kf0, dk, 0, 0, 0);
    dk = __builtin_amdgcn_mfma_f32_16x16x32_bf16(a1, kf1, dk, 0, 0, 0);
    __builtin_amdgcn_s_setprio(0);
    if (it + 2 < 16) stage_it(it + 2);
    uint32_t p0 = 0, p1 = 0;
#pragma unroll
    for (int i = 0; i < 4; ++i) {
      float gv = __expf(dg[i] * 0.125f);           // /sqrt(D)
      unsigned short u = f2bf(gv);
      lg[i] += bf2f(u);                            // sum the ROUNDED value (consistent)
      if (i < 2) p0 |= (uint32_t)u << (16 * i);
      else       p1 |= (uint32_t)u << (16 * (i - 2));
      stk[it][i] = dk[i];
    }
    stg[it][0] = p0;
    stg[it][1] = p1;
  }
#pragma unroll
  for (int m = 1; m < 16; m <<= 1) {
#pragma unroll
    for (int i = 0; i < 4; ++i) lg[i] += __shfl_xor(lg[i], m);
  }
  if (col == 0) {
#pragma unroll
    for (int i = 0; i < 4; ++i) red0[wave][quad * 4 + i] = lg[i];
  }
  __syncthreads();
  float ilg[4];
#pragma unroll
  for (int i = 0; i < 4; ++i) {
    int rr = quad * 4 + i;
    ilg[i] = 1.0f / (red0[0][rr] + red0[1][rr] + red0[2][rr] + red0[3][rr]);
  }

  // ---- pass 2 (register-only): combine + l_w ----
  float lw[4] = {0.f, 0.f, 0.f, 0.f};
#pragma unroll
  for (int it = 0; it < 16; ++it) {
#pragma unroll
    for (int i = 0; i < 4; ++i) {
      unsigned short u = (unsigned short)((i < 2 ? stg[it][0] >> (16 * i)
                                                 : stg[it][1] >> (16 * (i - 2))) & 0xffffu);
      float gv = bf2f(u) * ilg[i];
      float z = sa * stk[it][i] + sb * gv;
      float wv = __expf(z);
      stk[it][i] = wv;
      lw[i] += wv;
    }
  }
#pragma unroll
  for (int m = 1; m < 16; m <<= 1) {
#pragma unroll
    for (int i = 0; i < 4; ++i) lw[i] += __shfl_xor(lw[i], m);
  }
  if (col == 0) {
#pragma unroll
    for (int i = 0; i < 4; ++i) red1[wave][quad * 4 + i] = lw[i];
  }
  __syncthreads();
  float ilw[4];
#pragma unroll
  for (int i = 0; i < 4; ++i) {
    int rr = quad * 4 + i;
    ilw[i] = 1.0f / (red1[0][rr] + red1[1][rr] + red1[2][rr] + red1[3][rr]);
  }

  // ---- pass 3: normalize + write wt (t, s) layout ----
  __hip_bfloat16* wrow = wt + ((size_t)bh * S_LEN + t_base + col) * S_LEN + s0 + quad * 4;
#pragma unroll
  for (int it = 0; it < 16; ++it) {
    us4 o;
#pragma unroll
    for (int i = 0; i < 4; ++i) o[i] = f2bf(stk[it][i] * ilw[i]);
    *reinterpret_cast<us4*>(wrow + (size_t)it * 16 * S_LEN) = o;
  }
}

// ---------------------------------------------------------------------------
// K4: out[bh, t, e] = sum_s wt[bh][t][s] * tT[b][e][s]   (BT-GEMM)
// v2: double-buffered LDS (2x32 KB) + counted s_waitcnt vmcnt(8) (prefetch
//     stays in flight across the barrier; raw s_barrier, NOT __syncthreads,
//     which would drain vmcnt to 0) + T2 XOR swizzle byte^=((row&7)<<4)
//     (rule 21: linear LDS dest + inverse-swizzled GLOBAL source col +
//     swizzled fragment read) -> ds_read_b128 at the 32-bank structural
//     floor instead of 16-way conflicts. T5 setprio around MFMA cluster.
// ---------------------------------------------------------------------------
__global__ __launch_bounds__(256) void k_outgemm(const __hip_bfloat16* __restrict__ wt,
                                                 const __hip_bfloat16* __restrict__ tT,
                                                 float* __restrict__ out) {
  __shared__ __hip_bfloat16 As[2][128 * 64];       // [buf][m][k] 2x16 KB
  __shared__ __hip_bfloat16 Bs[2][128 * 64];       // [buf][n][k] 2x16 KB
  const int tid = threadIdx.x;
  const int wave = tid >> 6, lane = tid & 63;
  const int quad = lane >> 4, col = lane & 15;

  const int g = blockIdx.x;                        // 0..1023
  const int xcd = g & 7;
  const int local = g >> 3;                        // 0..127
  const int strip = xcd * 32 + (local >> 2);       // 0..255 = (bh, mtile)
  const int ntile = local & 3;
  const int bh = strip >> 3;
  const int mt = strip & 7;
  const int b = bh >> 3;
  const int m0 = mt * 128;                         // t
  const int n0 = ntile * 128;                      // e

  const __hip_bfloat16* Ag = wt + (size_t)bh * S_LEN * S_LEN;   // row stride S
  const __hip_bfloat16* Bg = tT + (size_t)b * E_DIM * S_LEN;    // row stride S
  const int mw = (wave >> 1) * 64, nw = (wave & 1) * 64;
  const int lrow = lane >> 3;                      // 0..7 (= dest row & 7)
  const int lcolswz = ((lane & 7) ^ lrow) * 8;     // inverse-swizzled src col

  f32x4 acc[4][4];
#pragma unroll
  for (int i = 0; i < 4; ++i)
#pragma unroll
    for (int j = 0; j < 4; ++j) acc[i][j] = (f32x4){0.f, 0.f, 0.f, 0.f};

  // stage one K-tile (8 global_load_lds per thread-wave: 4 A + 4 B)
  auto stage = [&](int kt, int buf) {
    const int k0 = kt * 64;
#pragma unroll
    for (int j = 0; j < 4; ++j) {
      const int rbase = j * 32 + wave * 8;
      const __hip_bfloat16* gpA = Ag + (size_t)(m0 + rbase + lrow) * S_LEN + k0 + lcolswz;
      __builtin_amdgcn_global_load_lds((gas_uint*)gpA,
                                       (las_uint*)(&As[buf][rbase * 64]), 16, 0, 0);
      const __hip_bfloat16* gpB = Bg + (size_t)(n0 + rbase + lrow) * S_LEN + k0 + lcolswz;
      __builtin_amdgcn_global_load_lds((gas_uint*)gpB,
                                       (las_uint*)(&Bs[buf][rbase * 64]), 16, 0, 0);
    }
  };

  const int swz = (col & 7) << 4;                  // read-side swizzle (row&7 = col&7)
  auto compute = [&](int buf) {
    const char* Ab = (const char*)&As[buf][0];
    const char* Bb = (const char*)&Bs[buf][0];
    __builtin_amdgcn_s_setprio(1);
#pragma unroll
    for (int ks = 0; ks < 2; ++ks) {
      s16x8 af[4], bfr[4];
#pragma unroll
      for (int i = 0; i < 4; ++i)
        af[i] = *reinterpret_cast<const s16x8*>(
            Ab + (size_t)(mw + i * 16 + col) * 128 + ((ks * 64 + quad * 16) ^ swz));
#pragma unroll
      for (int i = 0; i < 4; ++i)
        bfr[i] = *reinterpret_cast<const s16x8*>(
            Bb + (size_t)(nw + i * 16 + col) * 128 + ((ks * 64 + quad * 16) ^ swz));
#pragma unroll
      for (int mi = 0; mi < 4; ++mi)
#pragma unroll
        for (int ni = 0; ni < 4; ++ni)
          acc[mi][ni] = __builtin_amdgcn_mfma_f32_16x16x32_bf16(af[mi], bfr[ni], acc[mi][ni], 0, 0, 0);
    }
    __builtin_amdgcn_s_setprio(0);
  };

  stage(0, 0);
#pragma unroll 1
  for (int kt = 0; kt < 15; ++kt) {
    stage(kt + 1, (kt + 1) & 1);                   // prefetch next tile (8 ops in flight)
    asm volatile("s_waitcnt vmcnt(8)" ::: "memory"); // wait ONLY for buf[kt]'s 8 ops
    __builtin_amdgcn_s_barrier();                  // all waves' buf[kt] data landed
    compute(kt & 1);
    asm volatile("" ::: "memory");
    __builtin_amdgcn_s_barrier();                  // reads done before buf[kt] overwrite
  }
  asm volatile("s_waitcnt vmcnt(0)" ::: "memory"); // last tile: drain
  __builtin_amdgcn_s_barrier();
  compute(1);                                      // kt = 15 -> buf 1

  // epilogue: C row = quad*4+reg (m), col = lane&15 (n)
#pragma unroll
  for (int mi = 0; mi < 4; ++mi)
#pragma unroll
    for (int ni = 0; ni < 4; ++ni)
#pragma unroll
      for (int i = 0; i < 4; ++i) {
        int m = m0 + mw + mi * 16 + quad * 4 + i;
        int n = n0 + nw + ni * 16 + col;
        out[((size_t)bh * S_LEN + m) * E_DIM + n] = acc[mi][ni][i];
      }
}

// ---------------------------------------------------------------------------
// Workspace layout (bytes):
//   qb  [0,   4M)   (BH,S,D) bf16
//   kb  [4M,  8M)
//   cb  [8M, 12M)
//   tT  [12M,16M)   (B,E,S) bf16
//   wt  [16M,80M)   (BH,S_t,S_s) bf16
// ---------------------------------------------------------------------------
extern "C" void kernel_launch(void* const* d_in, const int* in_sizes, int n_in,
                              void* d_out, int out_size, void* d_ws, size_t ws_size,
                              hipStream_t stream) {
  (void)in_sizes; (void)n_in; (void)out_size; (void)ws_size;
  const float* src = (const float*)d_in[0];
  const float* tgt = (const float*)d_in[1];
  const float* enc = (const float*)d_in[2];
  const float* pal = (const float*)d_in[3];
  const float* pbe = (const float*)d_in[4];
  const float* pga = (const float*)d_in[5];
  float* out = (float*)d_out;

  char* ws = (char*)d_ws;
  __hip_bfloat16* qb = (__hip_bfloat16*)(ws);
  __hip_bfloat16* kb = (__hip_bfloat16*)(ws + ((size_t)4 << 20));
  __hip_bfloat16* cb = (__hip_bfloat16*)(ws + ((size_t)8 << 20));
  __hip_bfloat16* tT = (__hip_bfloat16*)(ws + ((size_t)12 << 20));
  __hip_bfloat16* wt = (__hip_bfloat16*)(ws + ((size_t)16 << 20));

  // Fused prep: recurrence (blocks 0..7) + pack + transpose
  k_prep<<<NB_RECUR + NB_PACK + NB_TR, 256, 0, stream>>>(src, tgt, enc, qb, kb, cb, tT);
  // K3: weights (1D swizzled grid, 4 bh per XCD)
  k_weights<<<dim3((S_LEN / 16) * BH_NUM), 256, 0, stream>>>(qb, kb, cb, wt, pal, pbe, pga);
  // K4: output GEMM (1D swizzled grid)
  k_outgemm<<<dim3((E_DIM / 128) * (S_LEN / 128) * BH_NUM), 256, 0, stream>>>(wt, tT, out);
}